// Round 3
// baseline (25.528 us; speedup 1.0000x reference)
//
#include <hip/hip_runtime.h>

#define BATCH  256
#define NV     5000
#define NCLS   20000
#define NCHUNK 1000
#define CHUNK  20          // NCHUNK * CHUNK == NCLS
#define TB     64

// ---------- transpose x[256][5000] -> xT[5000][256] ----------
__global__ __launch_bounds__(256)
void bmn_transpose(const float* __restrict__ x, float* __restrict__ xT) {
    __shared__ float tile[TB][TB + 1];
    const int v0 = blockIdx.x * TB;
    const int b0 = blockIdx.y * TB;
    const int tx = threadIdx.x & 63;
    const int ty = threadIdx.x >> 6;
    #pragma unroll
    for (int j = 0; j < TB; j += 4) {
        const int v = v0 + tx;
        tile[j + ty][tx] = (v < NV) ? x[(b0 + j + ty) * NV + v] : 0.f;
    }
    __syncthreads();
    #pragma unroll
    for (int j = 0; j < TB; j += 4) {
        const int v = v0 + j + ty;
        if (v < NV) xT[v * BATCH + b0 + tx] = tile[tx][j + ty];  // stride-65: conflict-free
    }
}

// ---------- main: lane = batch row, clause uniform per wave ----------
__device__ __forceinline__ float eval_c(float f0, float d0, float f2, float d1,
                                        float f4, float d2, float f6, float d3,
                                        float p0, float p1, float p2) {
    float t0 = fmaf(d0, p2, f0);
    float t1 = fmaf(d1, p2, f2);
    float t2 = fmaf(d2, p2, f4);
    float t3 = fmaf(d3, p2, f6);
    float u0 = fmaf(t1 - t0, p1, t0);
    float u1 = fmaf(t3 - t2, p1, t2);
    return fmaf(u1 - u0, p0, u0);
}

__global__ __launch_bounds__(256)
void bmn_main(const float* __restrict__ xT,
              const int*   __restrict__ vars,
              const float* __restrict__ factors,
              float* __restrict__ partial) {
    const int cs = blockIdx.x;           // clause chunk
    const int b  = threadIdx.x;          // batch row (lane = b & 63)
    const int cbase = cs * CHUNK;
    float acc = 0.f;
    #pragma unroll 4
    for (int k = 0; k < CHUNK; ++k) {
        const int c = cbase + k;         // wave-uniform -> scalar loads
        const int v0 = vars[c * 3 + 0];
        const int v1 = vars[c * 3 + 1];
        const int v2 = vars[c * 3 + 2];
        const float4 fa = *reinterpret_cast<const float4*>(factors + c * 8);
        const float4 fb = *reinterpret_cast<const float4*>(factors + c * 8 + 4);
        const float p0 = xT[v0 * BATCH + b];   // coalesced vector load
        const float p1 = xT[v1 * BATCH + b];
        const float p2 = xT[v2 * BATCH + b];
        const float d0 = fa.y - fa.x, d1 = fa.w - fa.z;
        const float d2 = fb.y - fb.x, d3 = fb.w - fb.z;
        acc += eval_c(fa.x, d0, fa.z, d1, fb.x, d2, fb.z, d3, p0, p1, p2);
    }
    partial[cs * BATCH + b] = acc;       // coalesced
}

// ---------- reduce partial[NCHUNK][BATCH] -> out[BATCH] ----------
__global__ __launch_bounds__(256)
void bmn_reduce(const float* __restrict__ partial, float* __restrict__ out) {
    const int b = blockIdx.x;
    const int t = threadIdx.x;
    float s = 0.f;
    for (int cs = t; cs < NCHUNK; cs += 256)
        s += partial[cs * BATCH + b];
    for (int off = 32; off; off >>= 1)
        s += __shfl_down(s, off, 64);
    __shared__ float red[4];
    if ((t & 63) == 0) red[t >> 6] = s;
    __syncthreads();
    if (t == 0) out[b] = red[0] + red[1] + red[2] + red[3];
}

// ---------- fallback (ws too small): direct, correct, slower ----------
__global__ __launch_bounds__(256)
void bmn_fallback(const float* __restrict__ x,
                  const int*   __restrict__ vars,
                  const float* __restrict__ factors,
                  float* __restrict__ out) {
    const int b = blockIdx.x;
    const int t = threadIdx.x;
    const float* xb = x + b * NV;
    float acc = 0.f;
    for (int c = t; c < NCLS; c += 256) {
        const int v0 = vars[c * 3 + 0];
        const int v1 = vars[c * 3 + 1];
        const int v2 = vars[c * 3 + 2];
        const float4 fa = *reinterpret_cast<const float4*>(factors + c * 8);
        const float4 fb = *reinterpret_cast<const float4*>(factors + c * 8 + 4);
        const float d0 = fa.y - fa.x, d1 = fa.w - fa.z;
        const float d2 = fb.y - fb.x, d3 = fb.w - fb.z;
        acc += eval_c(fa.x, d0, fa.z, d1, fb.x, d2, fb.z, d3, xb[v0], xb[v1], xb[v2]);
    }
    for (int off = 32; off; off >>= 1)
        acc += __shfl_down(acc, off, 64);
    __shared__ float red[4];
    if ((t & 63) == 0) red[t >> 6] = acc;
    __syncthreads();
    if (t == 0) out[b] = red[0] + red[1] + red[2] + red[3];
}

extern "C" void kernel_launch(void* const* d_in, const int* in_sizes, int n_in,
                              void* d_out, int out_size, void* d_ws, size_t ws_size,
                              hipStream_t stream) {
    const float* x       = (const float*)d_in[0];
    // d_in[1] = binary_combinations (bit order hard-coded; verified rounds 1-2)
    const int*   vars    = (const int*)d_in[2];
    const float* factors = (const float*)d_in[3];
    float* out = (float*)d_out;

    const size_t xt_elems = (size_t)NV * BATCH;                 // 5.12 MB
    const size_t pp_elems = (size_t)NCHUNK * BATCH;             // 1.02 MB
    if (ws_size >= (xt_elems + pp_elems) * sizeof(float)) {
        float* xT      = (float*)d_ws;
        float* partial = xT + xt_elems;
        bmn_transpose<<<dim3((NV + TB - 1) / TB, BATCH / TB), 256, 0, stream>>>(x, xT);
        bmn_main<<<NCHUNK, 256, 0, stream>>>(xT, vars, factors, partial);
        bmn_reduce<<<BATCH, 256, 0, stream>>>(partial, out);
    } else {
        bmn_fallback<<<BATCH, 256, 0, stream>>>(x, vars, factors, out);
    }
}

// Round 4
// 14.111 us; speedup vs baseline: 1.8090x; 1.8090x over previous
//
#include <hip/hip_runtime.h>

#define BATCH 256
#define NV    5000
#define NCLS  20000
#define G     4           // batch rows per block, stored as 4 LDS planes
#define NT    512         // threads per block (8 waves)
#define NCH   8           // clause chunks
#define NVP   NV          // plane stride in floats

// Horner over the 3 selector bits; f-deltas precomputed (shared across rows).
__device__ __forceinline__ float eval_c(float f0, float d0, float f2, float d1,
                                        float f4, float d2, float f6, float d3,
                                        float p0, float p1, float p2) {
    float t0 = fmaf(d0, p2, f0);
    float t1 = fmaf(d1, p2, f2);
    float t2 = fmaf(d2, p2, f4);
    float t3 = fmaf(d3, p2, f6);
    float u0 = fmaf(t1 - t0, p1, t0);
    float u1 = fmaf(t3 - t2, p1, t2);
    return fmaf(u1 - u0, p0, u0);
}

// Block (bg, cs): batch rows [bg*G, bg*G+G), clause chunk cs of size cchunk.
// Partial sums -> outbuf[cs*BATCH + b].
__global__ __launch_bounds__(NT)
void bmn_main(const float* __restrict__ x,
              const int*   __restrict__ vars,
              const float* __restrict__ factors,
              float* __restrict__ outbuf,
              int cchunk) {
    __shared__ float xs[G * NVP];         // 80 KB: plane p at xs[p*NVP + v]
    const int bg  = blockIdx.x;
    const int cs  = blockIdx.y;
    const int tid = threadIdx.x;

    const float* xr = x + bg * G * NV;
    for (int i = tid; i < NV; i += NT) {  // 4 coalesced streams, conflict-free b32 writes
        xs[i]           = xr[i];
        xs[NVP + i]     = xr[NV + i];
        xs[2 * NVP + i] = xr[2 * NV + i];
        xs[3 * NVP + i] = xr[3 * NV + i];
    }
    __syncthreads();

    float acc[G] = {0.f, 0.f, 0.f, 0.f};
    const int cbase = cs * cchunk;
    const int cend  = cbase + cchunk;
    #pragma unroll 2
    for (int c = cbase + tid; c < cend; c += NT) {
        const int v0 = vars[c * 3 + 0];
        const int v1 = vars[c * 3 + 1];
        const int v2 = vars[c * 3 + 2];
        const float4 fa = *reinterpret_cast<const float4*>(factors + c * 8);
        const float4 fb = *reinterpret_cast<const float4*>(factors + c * 8 + 4);
        const float d0 = fa.y - fa.x, d1 = fa.w - fa.z;
        const float d2 = fb.y - fb.x, d3 = fb.w - fb.z;
        // 12 ds_read_b32: random bank start over all 32 banks -> ~2-way (free)
        #pragma unroll
        for (int p = 0; p < G; ++p) {
            const float p0 = xs[p * NVP + v0];
            const float p1 = xs[p * NVP + v1];
            const float p2 = xs[p * NVP + v2];
            acc[p] += eval_c(fa.x, d0, fa.z, d1, fb.x, d2, fb.z, d3, p0, p1, p2);
        }
    }

    // wave reduce (64 lanes)
    #pragma unroll
    for (int p = 0; p < G; ++p)
        for (int off = 32; off; off >>= 1)
            acc[p] += __shfl_down(acc[p], off, 64);
    __shared__ float red[NT / 64][G];
    if ((tid & 63) == 0) {
        const int w = tid >> 6;
        #pragma unroll
        for (int p = 0; p < G; ++p) red[w][p] = acc[p];
    }
    __syncthreads();
    if (tid < G) {
        float s = 0.f;
        #pragma unroll
        for (int w = 0; w < NT / 64; ++w) s += red[w][tid];
        outbuf[cs * BATCH + bg * G + tid] = s;
    }
}

__global__ __launch_bounds__(BATCH)
void bmn_reduce(const float* __restrict__ ws, float* __restrict__ out) {
    const int b = threadIdx.x;            // coalesced: b contiguous across lanes
    float s = 0.f;
    #pragma unroll
    for (int cs = 0; cs < NCH; ++cs) s += ws[cs * BATCH + b];
    out[b] = s;
}

extern "C" void kernel_launch(void* const* d_in, const int* in_sizes, int n_in,
                              void* d_out, int out_size, void* d_ws, size_t ws_size,
                              hipStream_t stream) {
    const float* x       = (const float*)d_in[0];
    // d_in[1] = binary_combinations (bit order hard-coded; verified rounds 1-3)
    const int*   vars    = (const int*)d_in[2];
    const float* factors = (const float*)d_in[3];
    float* out = (float*)d_out;

    if (ws_size >= (size_t)(NCH * BATCH) * sizeof(float)) {
        float* ws = (float*)d_ws;
        bmn_main<<<dim3(BATCH / G, NCH), NT, 0, stream>>>(x, vars, factors, ws, NCLS / NCH);
        bmn_reduce<<<1, BATCH, 0, stream>>>(ws, out);
    } else {
        // fallback: single chunk writes final sums directly (correct, slower)
        bmn_main<<<dim3(BATCH / G, 1), NT, 0, stream>>>(x, vars, factors, out, NCLS);
    }
}